// Round 10
// baseline (59.273 us; speedup 1.0000x reference)
//
#include <hip/hip_runtime.h>
#include <math.h>

#define ROWS_TOTAL 8192
#define KDIM 4096
#define NJ 25          // 4 pre + 4 post + 16 res + 1 ssq
#define NTHREADS 512

// primary-path geometry (KSPLIT=16)
#define KQ 256         // k per block
#define NS 8           // K-steps of 32
#define CHROWS 32      // rows per staged A-chunk
#define NCH 4          // 128 rows / CHROWS

typedef __attribute__((ext_vector_type(8))) short bf16x8;
typedef __attribute__((ext_vector_type(4))) float f32x4;

__device__ __forceinline__ unsigned cvt_pk_bf16(float lo, float hi) {
    unsigned r;
    asm("v_cvt_pk_bf16_f32 %0, %1, %2" : "=v"(r) : "v"(lo), "v"(hi));
    return r;
}

union BF { uint4 u4; bf16x8 h; };

// async global->LDS, 16B per lane, lane i lands at ldst + i*16 (linear dest)
#define GLL16(gsrc, ldst) \
  __builtin_amdgcn_global_load_lds( \
      (const __attribute__((address_space(1))) void*)(gsrc), \
      (__attribute__((address_space(3))) void*)(ldst), 16, 0, 0)

// ------------------------------------------------------------------
// Primary kernel (KSPLIT=16): coalesced-staged bf16 MFMA + fp32 ssq.
// grid = 64 row-groups x 16 k-slices, 512 threads (8 waves).
// A staged in 32-row x 1KB chunks via global_load_lds: ONE instruction
// = ONE row's full 1KB k-slice (64 lanes x 16B contiguous) -- the m13
// 6.3TB/s pattern. Source lane-perm (lane ^ (row&7)) pre-swizzles so
// ds_read_b128 fragment reads are conflict-free (both-sides swizzle).
// Waves split work per chunk: tile th=wave&1 (16 rows), K-half wave>>1.
// acc/ssq partials reduced across waves in LDS at the end.
// LDS: B-frags 16KB + A dbuf 64KB = 80KB -> 2 blocks/CU.
// ws layout: ws[slice][j(25)][row(8192)]  (unchanged)
// ------------------------------------------------------------------
__global__ __launch_bounds__(NTHREADS) void mhc_main16(
    const float* __restrict__ x,
    const float* __restrict__ rmsw,
    const float* __restrict__ phi_pre,
    const float* __restrict__ phi_post,
    const float* __restrict__ phi_res,
    float* __restrict__ ws)
{
    __shared__ uint4 bfrag[NS * 2 * 64];        // 16 KB
    __shared__ float Abuf[2][CHROWS * KQ];      // 2 x 32 KB

    const int t    = threadIdx.x;
    const int wave = t >> 6;
    const int lane = t & 63;
    const int bid  = blockIdx.x;
    const int g    = bid >> 4;     // row group 0..63
    const int q    = bid & 15;     // k slice 0..15
    const int kq0  = q * KQ;

    // ---- stage B fragments (one-time); FPT = 8*2*64/512 = 2 ----
    #pragma unroll
    for (int f = 0; f < 2; ++f) {
        const int fid = f * NTHREADS + t;
        const int s   = fid >> 7;               // K-step
        const int n   = (fid >> 6) & 1;         // col tile
        const int ln  = fid & 63;               // frag lane
        const int col = n * 16 + (ln & 15);
        const int kl  = s * 32 + 8 * (ln >> 4);
        float v[8];
        #pragma unroll
        for (int j = 0; j < 8; ++j) {
            const int k = kq0 + kl + j;
            float vv = 0.f;
            if (col < 4)       vv = rmsw[k] * phi_pre[k * 4 + col];
            else if (col < 8)  vv = rmsw[k] * phi_post[k * 4 + (col - 4)];
            else if (col < 24) vv = rmsw[k] * phi_res[k * 16 + (col - 8)];
            v[j] = vv;
        }
        uint4 pk;
        pk.x = cvt_pk_bf16(v[0], v[1]);
        pk.y = cvt_pk_bf16(v[2], v[3]);
        pk.z = cvt_pk_bf16(v[4], v[5]);
        pk.w = cvt_pk_bf16(v[6], v[7]);
        bfrag[(s * 2 + n) * 64 + ln] = pk;
    }

    // ---- prologue: stage chunk 0 (wave w -> rows 4w..4w+3) ----
    #pragma unroll
    for (int i = 0; i < 4; ++i) {
        const int rr = wave * 4 + i;                       // row in chunk
        const int grow = g * 128 + rr;                     // chunk 0
        GLL16(x + (size_t)grow * KDIM + kq0 + ((lane ^ (rr & 7)) << 2),
              &Abuf[0][rr * KQ]);
    }
    __syncthreads();   // drains vmcnt (gll) + lgkm (B writes)

    f32x4 acc[NCH][2];
    float ssqa[NCH];
    #pragma unroll
    for (int c = 0; c < NCH; ++c) {
        acc[c][0] = (f32x4){0.f, 0.f, 0.f, 0.f};
        acc[c][1] = (f32x4){0.f, 0.f, 0.f, 0.f};
        ssqa[c] = 0.f;
    }

    const int th = wave & 1;       // row tile within chunk
    const int kh = wave >> 1;      // K-half 0..3
    const int r  = th * 16 + (lane & 15);   // row in chunk for fragments

    #pragma unroll
    for (int c = 0; c < NCH; ++c) {
        // issue next chunk's stage first (overlaps with compute + barrier wait)
        if (c + 1 < NCH) {
            #pragma unroll
            for (int i = 0; i < 4; ++i) {
                const int rr = wave * 4 + i;
                const int grow = g * 128 + (c + 1) * CHROWS + rr;
                GLL16(x + (size_t)grow * KDIM + kq0 + ((lane ^ (rr & 7)) << 2),
                      &Abuf[(c + 1) & 1][rr * KQ]);
            }
        }
        const char* ab = (const char*)&Abuf[c & 1][0];
        #pragma unroll
        for (int u = 0; u < 2; ++u) {
            const int ks  = kh * 2 + u;                 // K-step 0..7
            const int s16 = ks * 8 + 2 * (lane >> 4);   // 16B slot
            const float4 f0 = *(const float4*)(ab + r * 1024 + ((s16 ^ (r & 7)) << 4));
            const float4 f1 = *(const float4*)(ab + r * 1024 + (((s16 + 1) ^ (r & 7)) << 4));
            ssqa[c] = fmaf(f0.x, f0.x, ssqa[c]);
            ssqa[c] = fmaf(f0.y, f0.y, ssqa[c]);
            ssqa[c] = fmaf(f0.z, f0.z, ssqa[c]);
            ssqa[c] = fmaf(f0.w, f0.w, ssqa[c]);
            ssqa[c] = fmaf(f1.x, f1.x, ssqa[c]);
            ssqa[c] = fmaf(f1.y, f1.y, ssqa[c]);
            ssqa[c] = fmaf(f1.z, f1.z, ssqa[c]);
            ssqa[c] = fmaf(f1.w, f1.w, ssqa[c]);
            BF af;
            af.u4.x = cvt_pk_bf16(f0.x, f0.y);
            af.u4.y = cvt_pk_bf16(f0.z, f0.w);
            af.u4.z = cvt_pk_bf16(f1.x, f1.y);
            af.u4.w = cvt_pk_bf16(f1.z, f1.w);
            BF b0, b1;
            b0.u4 = bfrag[(ks * 2 + 0) * 64 + lane];
            b1.u4 = bfrag[(ks * 2 + 1) * 64 + lane];
            acc[c][0] = __builtin_amdgcn_mfma_f32_16x16x32_bf16(af.h, b0.h, acc[c][0], 0, 0, 0);
            acc[c][1] = __builtin_amdgcn_mfma_f32_16x16x32_bf16(af.h, b1.h, acc[c][1], 0, 0, 0);
        }
        __syncthreads();   // next chunk staged AND this buffer fully consumed
    }

    // ssq: fold the 4 k-offset lane-groups (same row across l>>4)
    #pragma unroll
    for (int c = 0; c < NCH; ++c) {
        ssqa[c] += __shfl_xor(ssqa[c], 16);
        ssqa[c] += __shfl_xor(ssqa[c], 32);
    }

    // ---- cross-wave reduce in LDS (reuse Abuf[0]): [th][c][j(9)][lane] ----
    float* red = &Abuf[0][0];
    const int wq = wave >> 1;
    for (int p = 0; p < 4; ++p) {
        if (wq == p) {
            #pragma unroll
            for (int c = 0; c < NCH; ++c) {
                const int base = ((th * NCH + c) * 9) * 64 + lane;
                if (p == 0) {
                    #pragma unroll
                    for (int rj = 0; rj < 4; ++rj) red[base + rj * 64] = acc[c][0][rj];
                    #pragma unroll
                    for (int rj = 0; rj < 4; ++rj) red[base + (4 + rj) * 64] = acc[c][1][rj];
                    red[base + 8 * 64] = ssqa[c];
                } else {
                    #pragma unroll
                    for (int rj = 0; rj < 4; ++rj) red[base + rj * 64] += acc[c][0][rj];
                    #pragma unroll
                    for (int rj = 0; rj < 4; ++rj) red[base + (4 + rj) * 64] += acc[c][1][rj];
                    red[base + 8 * 64] += ssqa[c];
                }
            }
        }
        __syncthreads();
    }

    // ---- write-out: wave -> tile (th=wave&1, c=wave>>1); C/D layout as before ----
    {
        const int oth = wave & 1, oc = wave >> 1;
        const int base = ((oth * NCH + oc) * 9) * 64 + lane;
        float v[9];
        #pragma unroll
        for (int j = 0; j < 9; ++j) v[j] = red[base + j * 64];
        float* wsq = ws + (size_t)q * (NJ * ROWS_TOTAL);
        const int rbase = g * 128 + oc * CHROWS + oth * 16 + 4 * (lane >> 4);
        const int c0 = lane & 15;
        #pragma unroll
        for (int rj = 0; rj < 4; ++rj)
            wsq[c0 * ROWS_TOTAL + rbase + rj] = v[rj];
        if (c0 < 8) {
            #pragma unroll
            for (int rj = 0; rj < 4; ++rj)
                wsq[(16 + c0) * ROWS_TOTAL + rbase + rj] = v[4 + rj];
        }
        if (lane < 16)
            wsq[24 * ROWS_TOTAL + g * 128 + oc * CHROWS + oth * 16 + lane] = v[8];
    }
}

// ------------------------------------------------------------------
// Legacy fallback main (fragment-direct loads), only used if ws is tiny.
// ------------------------------------------------------------------
template<int KSPLIT>
__global__ __launch_bounds__(NTHREADS) void mhc_main_legacy(
    const float* __restrict__ x,
    const float* __restrict__ rmsw,
    const float* __restrict__ phi_pre,
    const float* __restrict__ phi_post,
    const float* __restrict__ phi_res,
    float* __restrict__ ws)
{
    constexpr int KQl = KDIM / KSPLIT;
    constexpr int NSl = KQl / 32;
    constexpr int FPT = NSl * 2 * 64 / NTHREADS;

    __shared__ uint4 bfragl[NSl * 2 * 64];

    const int t    = threadIdx.x;
    const int wave = t >> 6;
    const int lane = t & 63;
    const int bid  = blockIdx.x;
    const int g    = bid / KSPLIT;
    const int q    = bid % KSPLIT;
    const int kq0  = q * KQl;

    #pragma unroll
    for (int f = 0; f < FPT; ++f) {
        const int fid = f * NTHREADS + t;
        const int s   = fid >> 7;
        const int n   = (fid >> 6) & 1;
        const int ln  = fid & 63;
        const int col = n * 16 + (ln & 15);
        const int kl  = s * 32 + 8 * (ln >> 4);
        float v[8];
        #pragma unroll
        for (int j = 0; j < 8; ++j) {
            const int k = kq0 + kl + j;
            float vv = 0.f;
            if (col < 4)       vv = rmsw[k] * phi_pre[k * 4 + col];
            else if (col < 8)  vv = rmsw[k] * phi_post[k * 4 + (col - 4)];
            else if (col < 24) vv = rmsw[k] * phi_res[k * 16 + (col - 8)];
            v[j] = vv;
        }
        uint4 pk;
        pk.x = cvt_pk_bf16(v[0], v[1]);
        pk.y = cvt_pk_bf16(v[2], v[3]);
        pk.z = cvt_pk_bf16(v[4], v[5]);
        pk.w = cvt_pk_bf16(v[6], v[7]);
        bfragl[(s * 2 + n) * 64 + ln] = pk;
    }
    __syncthreads();

    const int row = g * 128 + wave * 16 + (lane & 15);
    const float* xr = x + (size_t)row * KDIM + kq0 + 8 * (lane >> 4);

    f32x4 acc0 = {0.f, 0.f, 0.f, 0.f};
    f32x4 acc1 = {0.f, 0.f, 0.f, 0.f};
    float ssq = 0.f;

    #pragma unroll 4
    for (int s = 0; s < NSl; ++s) {
        const float4 a0 = *(const float4*)(xr + 32 * s);
        const float4 a1 = *(const float4*)(xr + 32 * s + 4);
        ssq = fmaf(a0.x, a0.x, ssq); ssq = fmaf(a0.y, a0.y, ssq);
        ssq = fmaf(a0.z, a0.z, ssq); ssq = fmaf(a0.w, a0.w, ssq);
        ssq = fmaf(a1.x, a1.x, ssq); ssq = fmaf(a1.y, a1.y, ssq);
        ssq = fmaf(a1.z, a1.z, ssq); ssq = fmaf(a1.w, a1.w, ssq);
        BF af;
        af.u4.x = cvt_pk_bf16(a0.x, a0.y);
        af.u4.y = cvt_pk_bf16(a0.z, a0.w);
        af.u4.z = cvt_pk_bf16(a1.x, a1.y);
        af.u4.w = cvt_pk_bf16(a1.z, a1.w);
        BF b0, b1;
        b0.u4 = bfragl[(s * 2 + 0) * 64 + lane];
        b1.u4 = bfragl[(s * 2 + 1) * 64 + lane];
        acc0 = __builtin_amdgcn_mfma_f32_16x16x32_bf16(af.h, b0.h, acc0, 0, 0, 0);
        acc1 = __builtin_amdgcn_mfma_f32_16x16x32_bf16(af.h, b1.h, acc1, 0, 0, 0);
    }

    ssq += __shfl_xor(ssq, 16);
    ssq += __shfl_xor(ssq, 32);

    float* wsq = ws + (size_t)q * (NJ * ROWS_TOTAL);
    const int rbase = g * 128 + wave * 16 + 4 * (lane >> 4);
    const int c0 = lane & 15;
    #pragma unroll
    for (int rr = 0; rr < 4; ++rr)
        wsq[c0 * ROWS_TOTAL + rbase + rr] = acc0[rr];
    if (c0 < 8) {
        #pragma unroll
        for (int rr = 0; rr < 4; ++rr)
            wsq[(16 + c0) * ROWS_TOTAL + rbase + rr] = acc1[rr];
    }
    if (lane < 16)
        wsq[24 * ROWS_TOTAL + g * 128 + wave * 16 + lane] = ssq;
}

// ------------------------------------------------------------------
// Kernel 2 (fused reduce + epilogue): unchanged from R6 (known good).
// ------------------------------------------------------------------
__device__ __forceinline__ float sigmoidf_(float z) {
    return 1.f / (1.f + __expf(-z));
}

template<int KSPLIT>
__global__ __launch_bounds__(NTHREADS) void mhc_epi(
    const float* __restrict__ ws,
    const float* __restrict__ b_pre,
    const float* __restrict__ b_post,
    const float* __restrict__ b_res,
    const float* __restrict__ a_pre,
    const float* __restrict__ a_post,
    const float* __restrict__ a_res,
    float* __restrict__ out)
{
    __shared__ float sm[NJ * 64];
    const int t    = threadIdx.x;
    const int wave = t >> 6;
    const int lane = t & 63;
    const int r0   = blockIdx.x * 64;

    for (int j = wave; j < NJ; j += 8) {
        float s = 0.f;
        #pragma unroll
        for (int q = 0; q < KSPLIT; ++q)
            s += ws[(size_t)q * (NJ * ROWS_TOTAL) + (size_t)j * ROWS_TOTAL + r0 + lane];
        sm[j * 64 + lane] = s;
    }
    __syncthreads();

    if (t < 64) {
        const int r = r0 + t;
        float d[NJ];
        #pragma unroll
        for (int j = 0; j < NJ; ++j)
            d[j] = sm[j * 64 + t];

        const float scale = rsqrtf(d[24] * (1.0f / KDIM) + 1e-6f);
        const float ap  = a_pre[0] * scale;
        const float apo = a_post[0] * scale;
        const float ar  = a_res[0] * scale;

        float4 o0, o1;
        o0.x = sigmoidf_(fmaf(ap, d[0], b_pre[0]));
        o0.y = sigmoidf_(fmaf(ap, d[1], b_pre[1]));
        o0.z = sigmoidf_(fmaf(ap, d[2], b_pre[2]));
        o0.w = sigmoidf_(fmaf(ap, d[3], b_pre[3]));
        o1.x = 2.f * sigmoidf_(fmaf(apo, d[4], b_post[0]));
        o1.y = 2.f * sigmoidf_(fmaf(apo, d[5], b_post[1]));
        o1.z = 2.f * sigmoidf_(fmaf(apo, d[6], b_post[2]));
        o1.w = 2.f * sigmoidf_(fmaf(apo, d[7], b_post[3]));

        float m[16];
        #pragma unroll
        for (int i = 0; i < 16; ++i)
            m[i] = __expf(fmaf(ar, d[8 + i], b_res[i]));

        for (int it = 0; it < 20; ++it) {
            #pragma unroll
            for (int i = 0; i < 4; ++i) {
                const float s = m[4*i] + m[4*i+1] + m[4*i+2] + m[4*i+3];
                const float inv = 1.f / s;
                m[4*i] *= inv; m[4*i+1] *= inv; m[4*i+2] *= inv; m[4*i+3] *= inv;
            }
            #pragma unroll
            for (int i = 0; i < 4; ++i) {
                const float s = m[i] + m[4+i] + m[8+i] + m[12+i];
                const float inv = 1.f / s;
                m[i] *= inv; m[4+i] *= inv; m[8+i] *= inv; m[12+i] *= inv;
            }
        }

        float* o_pre  = out;
        float* o_post = out + 32768;
        float* o_res  = out + 65536;
        ((float4*)o_pre)[r]  = o0;
        ((float4*)o_post)[r] = o1;
        #pragma unroll
        for (int i = 0; i < 4; ++i)
            ((float4*)o_res)[r * 4 + i] = make_float4(m[4*i], m[4*i+1], m[4*i+2], m[4*i+3]);
    }
}

extern "C" void kernel_launch(void* const* d_in, const int* in_sizes, int n_in,
                              void* d_out, int out_size, void* d_ws, size_t ws_size,
                              hipStream_t stream) {
    const float* x      = (const float*)d_in[0];
    const float* rmsw   = (const float*)d_in[1];
    const float* ppre   = (const float*)d_in[2];
    const float* ppost  = (const float*)d_in[3];
    const float* pres   = (const float*)d_in[4];
    const float* b_pre  = (const float*)d_in[5];
    const float* b_post = (const float*)d_in[6];
    const float* b_res  = (const float*)d_in[7];
    const float* a_pre  = (const float*)d_in[8];
    const float* a_post = (const float*)d_in[9];
    const float* a_res  = (const float*)d_in[10];
    float* ws  = (float*)d_ws;
    float* out = (float*)d_out;

    const size_t need16 = (size_t)16 * NJ * ROWS_TOTAL * 4;   // 13.1 MB
    if (ws_size >= need16) {
        hipLaunchKernelGGL(mhc_main16, dim3(64 * 16), dim3(NTHREADS), 0, stream,
                           x, rmsw, ppre, ppost, pres, ws);
        hipLaunchKernelGGL((mhc_epi<16>), dim3(128), dim3(NTHREADS), 0, stream,
                           ws, b_pre, b_post, b_res, a_pre, a_post, a_res, out);
    } else {
        hipLaunchKernelGGL((mhc_main_legacy<4>), dim3(64 * 4), dim3(NTHREADS), 0, stream,
                           x, rmsw, ppre, ppost, pres, ws);
        hipLaunchKernelGGL((mhc_epi<4>), dim3(128), dim3(NTHREADS), 0, stream,
                           ws, b_pre, b_post, b_res, a_pre, a_post, a_res, out);
    }
}

// Round 11
// 48.984 us; speedup vs baseline: 1.2101x; 1.2101x over previous
//
#include <hip/hip_runtime.h>
#include <math.h>

#define ROWS_TOTAL 8192
#define KDIM 4096
#define NJ 25          // 4 pre + 4 post + 16 res + 1 ssq
#define BM 128         // rows per block (8 waves x 16 rows)
#define NTHREADS 512

typedef __attribute__((ext_vector_type(8))) short bf16x8;
typedef __attribute__((ext_vector_type(4))) float f32x4;

// gfx950 packed f32->bf16 (RNE); dst.lo=bf16(lo), dst.hi=bf16(hi)
__device__ __forceinline__ unsigned cvt_pk_bf16(float lo, float hi) {
    unsigned r;
    asm("v_cvt_pk_bf16_f32 %0, %1, %2" : "=v"(r) : "v"(lo), "v"(hi));
    return r;
}

union BF { uint4 u4; bf16x8 h; };

__device__ __forceinline__ float sigmoidf_(float z) {
    return 1.f / (1.f + __expf(-z));
}

// ------------------------------------------------------------------
// Kernel 1: bf16 MFMA projection + fp32 ssq (R5-best structure + cvt_pk).
// grid = 64 row-groups x KSPLIT k-slices. 512 threads (8 waves).
// KSPLIT=16: KQ=256, staged-B LDS = 16KB -> 4 blocks/CU -> 32 waves/CU.
// Direct per-fragment global loads (no main-loop barriers), unroll 4.
// NOTE: no min-waves launch bound (R1/R7: caps VGPR -> serialization);
// no LDS A-staging (R10: occupancy + barrier-drain cost > coalescing win).
// ws layout: ws[slice][j(25)][row(8192)]
// ------------------------------------------------------------------
template<int KSPLIT>
__global__ __launch_bounds__(NTHREADS) void mhc_main(
    const float* __restrict__ x,
    const float* __restrict__ rmsw,
    const float* __restrict__ phi_pre,
    const float* __restrict__ phi_post,
    const float* __restrict__ phi_res,
    float* __restrict__ ws)
{
    constexpr int KQ  = KDIM / KSPLIT;   // k per block
    constexpr int NS  = KQ / 32;         // K-steps
    constexpr int FPT = NS * 2 * 64 / NTHREADS;  // frags per thread

    __shared__ uint4 bfrag[NS * 2 * 64];

    const int t    = threadIdx.x;
    const int wave = t >> 6;
    const int lane = t & 63;
    const int bid  = blockIdx.x;
    const int g    = bid / KSPLIT;       // row group 0..63
    const int q    = bid % KSPLIT;       // k slice
    const int kq0  = q * KQ;

    // ---- stage B fragments (one-time) ----
    #pragma unroll
    for (int f = 0; f < FPT; ++f) {
        const int fid = f * NTHREADS + t;
        const int s   = fid >> 7;               // K-step
        const int n   = (fid >> 6) & 1;         // col tile
        const int ln  = fid & 63;               // frag lane
        const int col = n * 16 + (ln & 15);
        const int kl  = s * 32 + 8 * (ln >> 4);
        float v[8];
        #pragma unroll
        for (int j = 0; j < 8; ++j) {
            const int k = kq0 + kl + j;
            float vv = 0.f;
            if (col < 4)       vv = rmsw[k] * phi_pre[k * 4 + col];
            else if (col < 8)  vv = rmsw[k] * phi_post[k * 4 + (col - 4)];
            else if (col < 24) vv = rmsw[k] * phi_res[k * 16 + (col - 8)];
            v[j] = vv;
        }
        uint4 pk;
        pk.x = cvt_pk_bf16(v[0], v[1]);
        pk.y = cvt_pk_bf16(v[2], v[3]);
        pk.z = cvt_pk_bf16(v[4], v[5]);
        pk.w = cvt_pk_bf16(v[6], v[7]);
        bfrag[(s * 2 + n) * 64 + ln] = pk;
    }
    __syncthreads();

    // ---- main loop ----
    const int row = g * BM + wave * 16 + (lane & 15);
    const float* xr = x + (size_t)row * KDIM + kq0 + 8 * (lane >> 4);

    f32x4 acc0 = {0.f, 0.f, 0.f, 0.f};
    f32x4 acc1 = {0.f, 0.f, 0.f, 0.f};
    float ssq0 = 0.f, ssq1 = 0.f;

    #pragma unroll 4
    for (int s = 0; s < NS; ++s) {
        const float4 a0 = *(const float4*)(xr + 32 * s);
        const float4 a1 = *(const float4*)(xr + 32 * s + 4);
        ssq0 = fmaf(a0.x, a0.x, ssq0);
        ssq0 = fmaf(a0.y, a0.y, ssq0);
        ssq0 = fmaf(a0.z, a0.z, ssq0);
        ssq0 = fmaf(a0.w, a0.w, ssq0);
        ssq1 = fmaf(a1.x, a1.x, ssq1);
        ssq1 = fmaf(a1.y, a1.y, ssq1);
        ssq1 = fmaf(a1.z, a1.z, ssq1);
        ssq1 = fmaf(a1.w, a1.w, ssq1);
        BF af;
        af.u4.x = cvt_pk_bf16(a0.x, a0.y);
        af.u4.y = cvt_pk_bf16(a0.z, a0.w);
        af.u4.z = cvt_pk_bf16(a1.x, a1.y);
        af.u4.w = cvt_pk_bf16(a1.z, a1.w);
        BF b0, b1;
        b0.u4 = bfrag[(s * 2 + 0) * 64 + lane];
        b1.u4 = bfrag[(s * 2 + 1) * 64 + lane];
        acc0 = __builtin_amdgcn_mfma_f32_16x16x32_bf16(af.h, b0.h, acc0, 0, 0, 0);
        acc1 = __builtin_amdgcn_mfma_f32_16x16x32_bf16(af.h, b1.h, acc1, 0, 0, 0);
    }

    // ssq: combine the 4 k-offset groups (rows identical across l>>4)
    float ssq = ssq0 + ssq1;
    ssq += __shfl_xor(ssq, 16);
    ssq += __shfl_xor(ssq, 32);

    // ---- write partials: C/D layout col=lane&15, row=4*(lane>>4)+reg ----
    float* wsq = ws + (size_t)q * (NJ * ROWS_TOTAL);
    const int rbase = g * BM + wave * 16 + 4 * (lane >> 4);
    const int c0 = lane & 15;
    #pragma unroll
    for (int r = 0; r < 4; ++r)
        wsq[c0 * ROWS_TOTAL + rbase + r] = acc0[r];
    if (c0 < 8) {
        #pragma unroll
        for (int r = 0; r < 4; ++r)
            wsq[(16 + c0) * ROWS_TOTAL + rbase + r] = acc1[r];
    }
    if (lane < 16)
        wsq[24 * ROWS_TOTAL + g * BM + wave * 16 + lane] = ssq;
}

// ------------------------------------------------------------------
// Kernel 2 (epi-v2): fully-parallel reduce + lane-parallel Sinkhorn.
// 256 blocks x 512 threads; block owns 32 rows.
// Reduce: thread (j = t>>5, row = t&31), 2 rounds cover 25 j; 16
// coalesced slice-loads each (two 128B segments per wave-instr).
// Sinkhorn: one 4x4 cell per lane (32 rows x 16 cells = 512 lanes, all
// busy): row-norm = shfl_xor 1,2 in 4-lane groups; col-norm = 4,8.
// LDS row stride 33 to spread the 16-cell reads across banks.
// ------------------------------------------------------------------
template<int KSPLIT>
__global__ __launch_bounds__(NTHREADS) void mhc_epi2(
    const float* __restrict__ ws,
    const float* __restrict__ b_pre,
    const float* __restrict__ b_post,
    const float* __restrict__ b_res,
    const float* __restrict__ a_pre,
    const float* __restrict__ a_post,
    const float* __restrict__ a_res,
    float* __restrict__ out)
{
    __shared__ float sm[NJ * 33];
    const int t  = threadIdx.x;
    const int r0 = blockIdx.x * 32;

    // ---- slice reduction into sm[j*33 + row] ----
    {
        const int row = t & 31;
        const int j0  = t >> 5;          // 0..15
        float s0 = 0.f;
        #pragma unroll
        for (int q = 0; q < KSPLIT; ++q)
            s0 += ws[(size_t)q * (NJ * ROWS_TOTAL) + (size_t)j0 * ROWS_TOTAL + r0 + row];
        sm[j0 * 33 + row] = s0;
        const int j1 = 16 + j0;          // 16..31
        if (j1 < NJ) {
            float s1 = 0.f;
            #pragma unroll
            for (int q = 0; q < KSPLIT; ++q)
                s1 += ws[(size_t)q * (NJ * ROWS_TOTAL) + (size_t)j1 * ROWS_TOTAL + r0 + row];
            sm[j1 * 33 + row] = s1;
        }
    }
    __syncthreads();

    // ---- per-lane cell assignment ----
    const int wave = t >> 6;
    const int lane = t & 63;
    const int row  = wave * 4 + (lane >> 4);   // local row 0..31
    const int cell = lane & 15;                // i*4 + jc
    const int gr   = r0 + row;                 // global row

    const float scale = rsqrtf(sm[24 * 33 + row] * (1.0f / KDIM) + 1e-6f);

    // pre (cells 0-3) / post (cells 4-7) outputs
    if (cell < 4) {
        const float ap = a_pre[0] * scale;
        out[gr * 4 + cell] = sigmoidf_(fmaf(ap, sm[cell * 33 + row], b_pre[cell]));
    } else if (cell < 8) {
        const float apo = a_post[0] * scale;
        out[32768 + gr * 4 + (cell - 4)] =
            2.f * sigmoidf_(fmaf(apo, sm[cell * 33 + row], b_post[cell - 4]));
    }

    // Sinkhorn: one cell per lane
    const float ar = a_res[0] * scale;
    float m = __expf(fmaf(ar, sm[(8 + cell) * 33 + row], b_res[cell]));

    for (int it = 0; it < 20; ++it) {
        float s = m + __shfl_xor(m, 1);        // row sum (over jc)
        s += __shfl_xor(s, 2);
        m /= s;
        float c = m + __shfl_xor(m, 4);        // col sum (over i)
        c += __shfl_xor(c, 8);
        m /= c;
    }
    out[65536 + gr * 16 + cell] = m;
}

extern "C" void kernel_launch(void* const* d_in, const int* in_sizes, int n_in,
                              void* d_out, int out_size, void* d_ws, size_t ws_size,
                              hipStream_t stream) {
    const float* x      = (const float*)d_in[0];
    const float* rmsw   = (const float*)d_in[1];
    const float* ppre   = (const float*)d_in[2];
    const float* ppost  = (const float*)d_in[3];
    const float* pres   = (const float*)d_in[4];
    const float* b_pre  = (const float*)d_in[5];
    const float* b_post = (const float*)d_in[6];
    const float* b_res  = (const float*)d_in[7];
    const float* a_pre  = (const float*)d_in[8];
    const float* a_post = (const float*)d_in[9];
    const float* a_res  = (const float*)d_in[10];
    float* ws  = (float*)d_ws;
    float* out = (float*)d_out;

    const size_t need16 = (size_t)16 * NJ * ROWS_TOTAL * 4;   // 13.1 MB
    if (ws_size >= need16) {
        hipLaunchKernelGGL((mhc_main<16>), dim3(64 * 16), dim3(NTHREADS), 0, stream,
                           x, rmsw, ppre, ppost, pres, ws);
        hipLaunchKernelGGL((mhc_epi2<16>), dim3(256), dim3(NTHREADS), 0, stream,
                           ws, b_pre, b_post, b_res, a_pre, a_post, a_res, out);
    } else {
        hipLaunchKernelGGL((mhc_main<4>), dim3(64 * 4), dim3(NTHREADS), 0, stream,
                           x, rmsw, ppre, ppost, pres, ws);
        hipLaunchKernelGGL((mhc_epi2<4>), dim3(256), dim3(NTHREADS), 0, stream,
                           ws, b_pre, b_post, b_res, a_pre, a_post, a_res, out);
    }
}

// Round 12
// 41.831 us; speedup vs baseline: 1.4170x; 1.1710x over previous
//
#include <hip/hip_runtime.h>
#include <math.h>

#define ROWS_TOTAL 8192
#define KDIM 4096
#define NJ 25
#define BM 16            // rows per main block
#define NWAVE 16         // waves per main block (1024 threads)
#define NSW 8            // K-steps per wave (KDIM/32/NWAVE)

typedef __attribute__((ext_vector_type(8))) short bf16x8;
typedef __attribute__((ext_vector_type(4))) float f32x4;

// gfx950 packed f32->bf16 (RNE); dst.lo=bf16(lo), dst.hi=bf16(hi)
__device__ __forceinline__ unsigned cvt_pk_bf16(float lo, float hi) {
    unsigned r;
    asm("v_cvt_pk_bf16_f32 %0, %1, %2" : "=v"(r) : "v"(lo), "v"(hi));
    return r;
}

union BF { uint4 u4; bf16x8 h; };

__device__ __forceinline__ float sigmoidf_(float z) {
    return 1.f / (1.f + __expf(-z));
}

// ------------------------------------------------------------------
// Kernel 0: pack B = (rmsw * phi) into MFMA-fragment order, bf16.
// frag fid = s*2+n (s = K-step 0..127, n = col tile), lane ln:
//   col = n*16+(ln&15), k = 32s + 8*(ln>>4) + j, j=0..7.
// 16384 frags, one per thread. Output: 256 KB in ws (L2-resident after).
// ------------------------------------------------------------------
__global__ __launch_bounds__(512) void mhc_pack(
    const float* __restrict__ rmsw,
    const float* __restrict__ phi_pre,
    const float* __restrict__ phi_post,
    const float* __restrict__ phi_res,
    uint4* __restrict__ packed)
{
    const int fid = blockIdx.x * 512 + threadIdx.x;   // 0..16383
    const int s   = fid >> 7;
    const int n   = (fid >> 6) & 1;
    const int ln  = fid & 63;
    const int col = n * 16 + (ln & 15);
    const int kl  = s * 32 + 8 * (ln >> 4);
    float v[8];
    #pragma unroll
    for (int j = 0; j < 8; ++j) {
        const int k = kl + j;
        float vv = 0.f;
        if (col < 4)       vv = rmsw[k] * phi_pre[k * 4 + col];
        else if (col < 8)  vv = rmsw[k] * phi_post[k * 4 + (col - 4)];
        else if (col < 24) vv = rmsw[k] * phi_res[k * 16 + (col - 8)];
        v[j] = vv;
    }
    uint4 pk;
    pk.x = cvt_pk_bf16(v[0], v[1]);
    pk.y = cvt_pk_bf16(v[2], v[3]);
    pk.z = cvt_pk_bf16(v[4], v[5]);
    pk.w = cvt_pk_bf16(v[6], v[7]);
    packed[fid] = pk;
}

// ------------------------------------------------------------------
// Kernel 1: full-K fused projection + epilogue. 512 blocks x 1024 thr.
// Block owns rows g*16..g*16+15 for ALL k: wave w covers k in
// [256w, 256w+256) with the R5-proven inner loop (NS=8, unroll 4,
// direct x loads, B-frags from L2-resident packed buffer, no barriers
// in the loop). Cross-wave reduce in LDS, then per-cell Sinkhorn
// (16 rows x 16 cells = 256 threads) and direct out writes.
// No ws partials / no second pass / no fences (R7-R8 lesson).
// No min-waves launch bound (R1/R7 lesson). Target VGPR<=64.
// ------------------------------------------------------------------
__global__ __launch_bounds__(1024) void mhc_full(
    const float* __restrict__ x,
    const uint4* __restrict__ packed,
    const float* __restrict__ b_pre,
    const float* __restrict__ b_post,
    const float* __restrict__ b_res,
    const float* __restrict__ a_pre,
    const float* __restrict__ a_post,
    const float* __restrict__ a_res,
    float* __restrict__ out)
{
    __shared__ float red[NWAVE * 9 * 64];   // 36.9 KB

    const int t    = threadIdx.x;
    const int wave = t >> 6;               // 0..15 = k-slice
    const int lane = t & 63;
    const int g    = blockIdx.x;           // row group 0..511

    const int row = g * BM + (lane & 15);
    const float* xr = x + (size_t)row * KDIM + wave * 256 + 8 * (lane >> 4);
    const uint4* pb = packed + wave * (NSW * 2 * 64);

    f32x4 acc0 = {0.f, 0.f, 0.f, 0.f};
    f32x4 acc1 = {0.f, 0.f, 0.f, 0.f};
    float ssq0 = 0.f, ssq1 = 0.f;

    #pragma unroll 4
    for (int s = 0; s < NSW; ++s) {
        const float4 a0 = *(const float4*)(xr + 32 * s);
        const float4 a1 = *(const float4*)(xr + 32 * s + 4);
        ssq0 = fmaf(a0.x, a0.x, ssq0);
        ssq0 = fmaf(a0.y, a0.y, ssq0);
        ssq0 = fmaf(a0.z, a0.z, ssq0);
        ssq0 = fmaf(a0.w, a0.w, ssq0);
        ssq1 = fmaf(a1.x, a1.x, ssq1);
        ssq1 = fmaf(a1.y, a1.y, ssq1);
        ssq1 = fmaf(a1.z, a1.z, ssq1);
        ssq1 = fmaf(a1.w, a1.w, ssq1);
        BF af;
        af.u4.x = cvt_pk_bf16(a0.x, a0.y);
        af.u4.y = cvt_pk_bf16(a0.z, a0.w);
        af.u4.z = cvt_pk_bf16(a1.x, a1.y);
        af.u4.w = cvt_pk_bf16(a1.z, a1.w);
        BF b0, b1;
        b0.u4 = pb[(s * 2 + 0) * 64 + lane];
        b1.u4 = pb[(s * 2 + 1) * 64 + lane];
        acc0 = __builtin_amdgcn_mfma_f32_16x16x32_bf16(af.h, b0.h, acc0, 0, 0, 0);
        acc1 = __builtin_amdgcn_mfma_f32_16x16x32_bf16(af.h, b1.h, acc1, 0, 0, 0);
    }

    // fold the 4 k-offset lane groups (same row across l>>4)
    float ssq = ssq0 + ssq1;
    ssq += __shfl_xor(ssq, 16);
    ssq += __shfl_xor(ssq, 32);

    // ---- dump per-wave partials: red[wave][j(9)][lane] ----
    float* myred = red + wave * 576;
    #pragma unroll
    for (int r = 0; r < 4; ++r) myred[r * 64 + lane] = acc0[r];
    #pragma unroll
    for (int r = 0; r < 4; ++r) myred[(4 + r) * 64 + lane] = acc1[r];
    myred[8 * 64 + lane] = ssq;
    __syncthreads();

    // ---- reduce 16 wave-slices into slot 0 (576 sums, conflict-free) ----
    if (t < 576) {
        float s = red[t];
        #pragma unroll
        for (int q = 1; q < NWAVE; ++q)
            s += red[q * 576 + t];
        red[t] = s;
    }
    __syncthreads();

    // ---- epilogue: 16 rows x 16 cells = threads 0..255 ----
    // C/D layout: value(row rr, col c) = red[jslot*64 + li],
    //   jslot = (rr&3) + (c<16 ? 0 : 4), li = (c&15) + 16*(rr>>2).
    if (t < 256) {
        const int rr   = t >> 4;          // local row 0..15
        const int cell = t & 15;          // res cell i*4+jc
        const int gr   = g * BM + rr;

        const float scale = rsqrtf(red[8 * 64 + rr] * (1.0f / KDIM) + 1e-6f);
        const int li = 16 * (rr >> 2);
        const int j0 = rr & 3;

        if (cell < 4) {
            const float v = red[j0 * 64 + li + cell];
            out[gr * 4 + cell] = sigmoidf_(fmaf(a_pre[0] * scale, v, b_pre[cell]));
        } else if (cell < 8) {
            const float v = red[j0 * 64 + li + cell];
            out[32768 + gr * 4 + (cell - 4)] =
                2.f * sigmoidf_(fmaf(a_post[0] * scale, v, b_post[cell - 4]));
        }

        // res column 8+cell (acc0 cols 8-15, acc1 cols 0-7)
        const int col   = 8 + cell;
        const int jslot = j0 + (col < 16 ? 0 : 4);
        const float v   = red[jslot * 64 + (col & 15) + li];
        float m = __expf(fmaf(a_res[0] * scale, v, b_res[cell]));

        for (int it = 0; it < 20; ++it) {
            float s = m + __shfl_xor(m, 1);       // row sum over jc
            s += __shfl_xor(s, 2);
            m /= s;
            float c = m + __shfl_xor(m, 4);       // col sum over i
            c += __shfl_xor(c, 8);
            m /= c;
        }
        out[65536 + gr * 16 + cell] = m;
    }
}

// ------------------------------------------------------------------
// Legacy fallback (tiny ws): R11 pair, unchanged.
// ------------------------------------------------------------------
template<int KSPLIT>
__global__ __launch_bounds__(512) void mhc_main_legacy(
    const float* __restrict__ x,
    const float* __restrict__ rmsw,
    const float* __restrict__ phi_pre,
    const float* __restrict__ phi_post,
    const float* __restrict__ phi_res,
    float* __restrict__ ws)
{
    constexpr int KQ  = KDIM / KSPLIT;
    constexpr int NS  = KQ / 32;
    constexpr int FPT = NS * 2 * 64 / 512;

    __shared__ uint4 bfrag[NS * 2 * 64];

    const int t    = threadIdx.x;
    const int wave = t >> 6;
    const int lane = t & 63;
    const int bid  = blockIdx.x;
    const int g    = bid / KSPLIT;
    const int q    = bid % KSPLIT;
    const int kq0  = q * KQ;

    #pragma unroll
    for (int f = 0; f < FPT; ++f) {
        const int fid = f * 512 + t;
        const int s   = fid >> 7;
        const int n   = (fid >> 6) & 1;
        const int ln  = fid & 63;
        const int col = n * 16 + (ln & 15);
        const int kl  = s * 32 + 8 * (ln >> 4);
        float v[8];
        #pragma unroll
        for (int j = 0; j < 8; ++j) {
            const int k = kq0 + kl + j;
            float vv = 0.f;
            if (col < 4)       vv = rmsw[k] * phi_pre[k * 4 + col];
            else if (col < 8)  vv = rmsw[k] * phi_post[k * 4 + (col - 4)];
            else if (col < 24) vv = rmsw[k] * phi_res[k * 16 + (col - 8)];
            v[j] = vv;
        }
        uint4 pk;
        pk.x = cvt_pk_bf16(v[0], v[1]);
        pk.y = cvt_pk_bf16(v[2], v[3]);
        pk.z = cvt_pk_bf16(v[4], v[5]);
        pk.w = cvt_pk_bf16(v[6], v[7]);
        bfrag[(s * 2 + n) * 64 + ln] = pk;
    }
    __syncthreads();

    const int row = g * 128 + wave * 16 + (lane & 15);
    const float* xr = x + (size_t)row * KDIM + kq0 + 8 * (lane >> 4);

    f32x4 acc0 = {0.f, 0.f, 0.f, 0.f};
    f32x4 acc1 = {0.f, 0.f, 0.f, 0.f};
    float ssq = 0.f;

    #pragma unroll 4
    for (int s = 0; s < NS; ++s) {
        const float4 a0 = *(const float4*)(xr + 32 * s);
        const float4 a1 = *(const float4*)(xr + 32 * s + 4);
        ssq = fmaf(a0.x, a0.x, ssq); ssq = fmaf(a0.y, a0.y, ssq);
        ssq = fmaf(a0.z, a0.z, ssq); ssq = fmaf(a0.w, a0.w, ssq);
        ssq = fmaf(a1.x, a1.x, ssq); ssq = fmaf(a1.y, a1.y, ssq);
        ssq = fmaf(a1.z, a1.z, ssq); ssq = fmaf(a1.w, a1.w, ssq);
        BF af;
        af.u4.x = cvt_pk_bf16(a0.x, a0.y);
        af.u4.y = cvt_pk_bf16(a0.z, a0.w);
        af.u4.z = cvt_pk_bf16(a1.x, a1.y);
        af.u4.w = cvt_pk_bf16(a1.z, a1.w);
        BF b0, b1;
        b0.u4 = bfrag[(s * 2 + 0) * 64 + lane];
        b1.u4 = bfrag[(s * 2 + 1) * 64 + lane];
        acc0 = __builtin_amdgcn_mfma_f32_16x16x32_bf16(af.h, b0.h, acc0, 0, 0, 0);
        acc1 = __builtin_amdgcn_mfma_f32_16x16x32_bf16(af.h, b1.h, acc1, 0, 0, 0);
    }

    ssq += __shfl_xor(ssq, 16);
    ssq += __shfl_xor(ssq, 32);

    float* wsq = ws + (size_t)q * (NJ * ROWS_TOTAL);
    const int rbase = g * 128 + wave * 16 + 4 * (lane >> 4);
    const int c0 = lane & 15;
    #pragma unroll
    for (int r = 0; r < 4; ++r)
        wsq[c0 * ROWS_TOTAL + rbase + r] = acc0[r];
    if (c0 < 8) {
        #pragma unroll
        for (int r = 0; r < 4; ++r)
            wsq[(16 + c0) * ROWS_TOTAL + rbase + r] = acc1[r];
    }
    if (lane < 16)
        wsq[24 * ROWS_TOTAL + g * 128 + wave * 16 + lane] = ssq;
}

template<int KSPLIT>
__global__ __launch_bounds__(512) void mhc_epi2(
    const float* __restrict__ ws,
    const float* __restrict__ b_pre,
    const float* __restrict__ b_post,
    const float* __restrict__ b_res,
    const float* __restrict__ a_pre,
    const float* __restrict__ a_post,
    const float* __restrict__ a_res,
    float* __restrict__ out)
{
    __shared__ float sm[NJ * 33];
    const int t  = threadIdx.x;
    const int r0 = blockIdx.x * 32;

    {
        const int row = t & 31;
        const int j0  = t >> 5;
        float s0 = 0.f;
        #pragma unroll
        for (int q = 0; q < KSPLIT; ++q)
            s0 += ws[(size_t)q * (NJ * ROWS_TOTAL) + (size_t)j0 * ROWS_TOTAL + r0 + row];
        sm[j0 * 33 + row] = s0;
        const int j1 = 16 + j0;
        if (j1 < NJ) {
            float s1 = 0.f;
            #pragma unroll
            for (int q = 0; q < KSPLIT; ++q)
                s1 += ws[(size_t)q * (NJ * ROWS_TOTAL) + (size_t)j1 * ROWS_TOTAL + r0 + row];
            sm[j1 * 33 + row] = s1;
        }
    }
    __syncthreads();

    const int wave = t >> 6;
    const int lane = t & 63;
    const int row  = wave * 4 + (lane >> 4);
    const int cell = lane & 15;
    const int gr   = r0 + row;

    const float scale = rsqrtf(sm[24 * 33 + row] * (1.0f / KDIM) + 1e-6f);

    if (cell < 4) {
        out[gr * 4 + cell] = sigmoidf_(fmaf(a_pre[0] * scale, sm[cell * 33 + row], b_pre[cell]));
    } else if (cell < 8) {
        out[32768 + gr * 4 + (cell - 4)] =
            2.f * sigmoidf_(fmaf(a_post[0] * scale, sm[cell * 33 + row], b_post[cell - 4]));
    }

    float m = __expf(fmaf(a_res[0] * scale, sm[(8 + cell) * 33 + row], b_res[cell]));
    for (int it = 0; it < 20; ++it) {
        float s = m + __shfl_xor(m, 1);
        s += __shfl_xor(s, 2);
        m /= s;
        float c = m + __shfl_xor(m, 4);
        c += __shfl_xor(c, 8);
        m /= c;
    }
    out[65536 + gr * 16 + cell] = m;
}

extern "C" void kernel_launch(void* const* d_in, const int* in_sizes, int n_in,
                              void* d_out, int out_size, void* d_ws, size_t ws_size,
                              hipStream_t stream) {
    const float* x      = (const float*)d_in[0];
    const float* rmsw   = (const float*)d_in[1];
    const float* ppre   = (const float*)d_in[2];
    const float* ppost  = (const float*)d_in[3];
    const float* pres   = (const float*)d_in[4];
    const float* b_pre  = (const float*)d_in[5];
    const float* b_post = (const float*)d_in[6];
    const float* b_res  = (const float*)d_in[7];
    const float* a_pre  = (const float*)d_in[8];
    const float* a_post = (const float*)d_in[9];
    const float* a_res  = (const float*)d_in[10];
    float* out = (float*)d_out;

    if (ws_size >= (size_t)16384 * 16) {   // 256 KB for packed B
        uint4* packed = (uint4*)d_ws;
        hipLaunchKernelGGL(mhc_pack, dim3(32), dim3(512), 0, stream,
                           rmsw, ppre, ppost, pres, packed);
        hipLaunchKernelGGL(mhc_full, dim3(512), dim3(1024), 0, stream,
                           x, packed, b_pre, b_post, b_res,
                           a_pre, a_post, a_res, out);
    } else {
        float* ws = (float*)d_ws;          // needs 3.3 MB
        hipLaunchKernelGGL((mhc_main_legacy<4>), dim3(64 * 4), dim3(512), 0, stream,
                           x, rmsw, ppre, ppost, pres, ws);
        hipLaunchKernelGGL((mhc_epi2<4>), dim3(256), dim3(512), 0, stream,
                           ws, b_pre, b_post, b_res, a_pre, a_post, a_res, out);
    }
}

// Round 13
// 41.027 us; speedup vs baseline: 1.4447x; 1.0196x over previous
//
#include <hip/hip_runtime.h>
#include <math.h>

#define ROWS_TOTAL 8192
#define KDIM 4096
#define NJ 25
#define BM 32            // rows per main block (two 16-row tiles)
#define NWAVE 16         // waves per main block (1024 threads)
#define NSW 8            // K-steps per wave (KDIM/32/NWAVE)

typedef __attribute__((ext_vector_type(8))) short bf16x8;
typedef __attribute__((ext_vector_type(4))) float f32x4;

// gfx950 packed f32->bf16 (RNE); dst.lo=bf16(lo), dst.hi=bf16(hi)
__device__ __forceinline__ unsigned cvt_pk_bf16(float lo, float hi) {
    unsigned r;
    asm("v_cvt_pk_bf16_f32 %0, %1, %2" : "=v"(r) : "v"(lo), "v"(hi));
    return r;
}

union BF { uint4 u4; bf16x8 h; };

__device__ __forceinline__ float sigmoidf_(float z) {
    return 1.f / (1.f + __expf(-z));
}

// ------------------------------------------------------------------
// Kernel 0: pack B = (rmsw * phi) into MFMA-fragment order, bf16.
// (unchanged from R12)
// ------------------------------------------------------------------
__global__ __launch_bounds__(512) void mhc_pack(
    const float* __restrict__ rmsw,
    const float* __restrict__ phi_pre,
    const float* __restrict__ phi_post,
    const float* __restrict__ phi_res,
    uint4* __restrict__ packed)
{
    const int fid = blockIdx.x * 512 + threadIdx.x;   // 0..16383
    const int s   = fid >> 7;
    const int n   = (fid >> 6) & 1;
    const int ln  = fid & 63;
    const int col = n * 16 + (ln & 15);
    const int kl  = s * 32 + 8 * (ln >> 4);
    float v[8];
    #pragma unroll
    for (int j = 0; j < 8; ++j) {
        const int k = kl + j;
        float vv = 0.f;
        if (col < 4)       vv = rmsw[k] * phi_pre[k * 4 + col];
        else if (col < 8)  vv = rmsw[k] * phi_post[k * 4 + (col - 4)];
        else if (col < 24) vv = rmsw[k] * phi_res[k * 16 + (col - 8)];
        v[j] = vv;
    }
    uint4 pk;
    pk.x = cvt_pk_bf16(v[0], v[1]);
    pk.y = cvt_pk_bf16(v[2], v[3]);
    pk.z = cvt_pk_bf16(v[4], v[5]);
    pk.w = cvt_pk_bf16(v[6], v[7]);
    packed[fid] = pk;
}

// ------------------------------------------------------------------
// Kernel 1: full-K fused projection + epilogue, BM=32 (two row tiles).
// 256 blocks x 1024 threads (1 block/CU, 16 waves/CU). Wave w covers
// k in [256w, 256w+256); per K-step: 4 x-loads + 2 B-loads + 4 MFMAs
// (B amortized over two row tiles -> half the L2 B-traffic and fewer
// VMEM instructions per x-byte than R12's BM=16).
// Cross-wave reduce in LDS (72 KB), then 32 rows x 16 cells = 512
// threads run the per-cell Sinkhorn and write out directly.
// No min-waves bound (R1/R7); no fences (R7/R8).
// ------------------------------------------------------------------
__global__ __launch_bounds__(1024) void mhc_full(
    const float* __restrict__ x,
    const uint4* __restrict__ packed,
    const float* __restrict__ b_pre,
    const float* __restrict__ b_post,
    const float* __restrict__ b_res,
    const float* __restrict__ a_pre,
    const float* __restrict__ a_post,
    const float* __restrict__ a_res,
    float* __restrict__ out)
{
    __shared__ float red[NWAVE * 2 * 9 * 64];   // 73.7 KB

    const int t    = threadIdx.x;
    const int wave = t >> 6;               // 0..15 = k-slice
    const int lane = t & 63;
    const int g    = blockIdx.x;           // row group 0..255

    const int row0 = g * BM + (lane & 15);         // tile 0 row
    const float* xr0 = x + (size_t)row0 * KDIM + wave * 256 + 8 * (lane >> 4);
    const float* xr1 = xr0 + (size_t)16 * KDIM;    // tile 1 row
    const uint4* pb = packed + wave * (NSW * 2 * 64);

    f32x4 acc00 = {0.f, 0.f, 0.f, 0.f};
    f32x4 acc01 = {0.f, 0.f, 0.f, 0.f};
    f32x4 acc10 = {0.f, 0.f, 0.f, 0.f};
    f32x4 acc11 = {0.f, 0.f, 0.f, 0.f};
    float ssqt0 = 0.f, ssqt1 = 0.f;

    #pragma unroll 4
    for (int s = 0; s < NSW; ++s) {
        const float4 p0 = *(const float4*)(xr0 + 32 * s);
        const float4 p1 = *(const float4*)(xr0 + 32 * s + 4);
        const float4 q0 = *(const float4*)(xr1 + 32 * s);
        const float4 q1 = *(const float4*)(xr1 + 32 * s + 4);
        BF b0, b1;
        b0.u4 = pb[(s * 2 + 0) * 64 + lane];
        b1.u4 = pb[(s * 2 + 1) * 64 + lane];

        ssqt0 = fmaf(p0.x, p0.x, ssqt0);
        ssqt0 = fmaf(p0.y, p0.y, ssqt0);
        ssqt0 = fmaf(p0.z, p0.z, ssqt0);
        ssqt0 = fmaf(p0.w, p0.w, ssqt0);
        ssqt0 = fmaf(p1.x, p1.x, ssqt0);
        ssqt0 = fmaf(p1.y, p1.y, ssqt0);
        ssqt0 = fmaf(p1.z, p1.z, ssqt0);
        ssqt0 = fmaf(p1.w, p1.w, ssqt0);
        ssqt1 = fmaf(q0.x, q0.x, ssqt1);
        ssqt1 = fmaf(q0.y, q0.y, ssqt1);
        ssqt1 = fmaf(q0.z, q0.z, ssqt1);
        ssqt1 = fmaf(q0.w, q0.w, ssqt1);
        ssqt1 = fmaf(q1.x, q1.x, ssqt1);
        ssqt1 = fmaf(q1.y, q1.y, ssqt1);
        ssqt1 = fmaf(q1.z, q1.z, ssqt1);
        ssqt1 = fmaf(q1.w, q1.w, ssqt1);

        BF af0, af1;
        af0.u4.x = cvt_pk_bf16(p0.x, p0.y);
        af0.u4.y = cvt_pk_bf16(p0.z, p0.w);
        af0.u4.z = cvt_pk_bf16(p1.x, p1.y);
        af0.u4.w = cvt_pk_bf16(p1.z, p1.w);
        af1.u4.x = cvt_pk_bf16(q0.x, q0.y);
        af1.u4.y = cvt_pk_bf16(q0.z, q0.w);
        af1.u4.z = cvt_pk_bf16(q1.x, q1.y);
        af1.u4.w = cvt_pk_bf16(q1.z, q1.w);

        acc00 = __builtin_amdgcn_mfma_f32_16x16x32_bf16(af0.h, b0.h, acc00, 0, 0, 0);
        acc01 = __builtin_amdgcn_mfma_f32_16x16x32_bf16(af0.h, b1.h, acc01, 0, 0, 0);
        acc10 = __builtin_amdgcn_mfma_f32_16x16x32_bf16(af1.h, b0.h, acc10, 0, 0, 0);
        acc11 = __builtin_amdgcn_mfma_f32_16x16x32_bf16(af1.h, b1.h, acc11, 0, 0, 0);
    }

    // fold the 4 k-offset lane groups (same row across l>>4)
    ssqt0 += __shfl_xor(ssqt0, 16);
    ssqt0 += __shfl_xor(ssqt0, 32);
    ssqt1 += __shfl_xor(ssqt1, 16);
    ssqt1 += __shfl_xor(ssqt1, 32);

    // ---- dump per-wave partials: red[wave][tile][j(9)][lane] ----
    float* myred = red + wave * 1152;
    #pragma unroll
    for (int r = 0; r < 4; ++r) myred[r * 64 + lane] = acc00[r];
    #pragma unroll
    for (int r = 0; r < 4; ++r) myred[(4 + r) * 64 + lane] = acc01[r];
    myred[8 * 64 + lane] = ssqt0;
    #pragma unroll
    for (int r = 0; r < 4; ++r) myred[576 + r * 64 + lane] = acc10[r];
    #pragma unroll
    for (int r = 0; r < 4; ++r) myred[576 + (4 + r) * 64 + lane] = acc11[r];
    myred[576 + 8 * 64 + lane] = ssqt1;
    __syncthreads();

    // ---- reduce 16 wave-slices into slot 0 (1152 sums) ----
    for (int i = t; i < 1152; i += 1024) {
        float s = red[i];
        #pragma unroll
        for (int q = 1; q < NWAVE; ++q)
            s += red[q * 1152 + i];
        red[i] = s;
    }
    __syncthreads();

    // ---- epilogue: 32 rows x 16 cells = threads 0..511 ----
    // value(local row lr, col c) = red[tile*576 + jslot*64 + li],
    //   jslot = (lr&3) + (c<16 ? 0 : 4), li = (c&15) + 16*(lr>>2).
    if (t < 512) {
        const int rr   = t >> 4;          // block row 0..31
        const int cell = t & 15;          // res cell i*4+jc
        const int tile = rr >> 4;
        const int lr   = rr & 15;
        const int gr   = g * BM + rr;
        const float* rb = red + tile * 576;

        const float scale = rsqrtf(rb[8 * 64 + lr] * (1.0f / KDIM) + 1e-6f);
        const int li = 16 * (lr >> 2);
        const int j0 = lr & 3;

        if (cell < 4) {
            const float v = rb[j0 * 64 + li + cell];
            out[gr * 4 + cell] = sigmoidf_(fmaf(a_pre[0] * scale, v, b_pre[cell]));
        } else if (cell < 8) {
            const float v = rb[j0 * 64 + li + cell];
            out[32768 + gr * 4 + (cell - 4)] =
                2.f * sigmoidf_(fmaf(a_post[0] * scale, v, b_post[cell - 4]));
        }

        // res column 8+cell (acc*0 holds cols 0-15, acc*1 cols 16-31)
        const int col   = 8 + cell;
        const int jslot = j0 + (col < 16 ? 0 : 4);
        const float v   = rb[jslot * 64 + (col & 15) + li];
        float m = __expf(fmaf(a_res[0] * scale, v, b_res[cell]));

        for (int it = 0; it < 20; ++it) {
            float s = m + __shfl_xor(m, 1);       // row sum over jc
            s += __shfl_xor(s, 2);
            m /= s;
            float c = m + __shfl_xor(m, 4);       // col sum over i
            c += __shfl_xor(c, 8);
            m /= c;
        }
        out[65536 + gr * 16 + cell] = m;
    }
}

// ------------------------------------------------------------------
// Legacy fallback (tiny ws): unchanged.
// ------------------------------------------------------------------
template<int KSPLIT>
__global__ __launch_bounds__(512) void mhc_main_legacy(
    const float* __restrict__ x,
    const float* __restrict__ rmsw,
    const float* __restrict__ phi_pre,
    const float* __restrict__ phi_post,
    const float* __restrict__ phi_res,
    float* __restrict__ ws)
{
    constexpr int KQ  = KDIM / KSPLIT;
    constexpr int NS  = KQ / 32;
    constexpr int FPT = NS * 2 * 64 / 512;

    __shared__ uint4 bfrag[NS * 2 * 64];

    const int t    = threadIdx.x;
    const int wave = t >> 6;
    const int lane = t & 63;
    const int bid  = blockIdx.x;
    const int g    = bid / KSPLIT;
    const int q    = bid % KSPLIT;
    const int kq0  = q * KQ;

    #pragma unroll
    for (int f = 0; f < FPT; ++f) {
        const int fid = f * 512 + t;
        const int s   = fid >> 7;
        const int n   = (fid >> 6) & 1;
        const int ln  = fid & 63;
        const int col = n * 16 + (ln & 15);
        const int kl  = s * 32 + 8 * (ln >> 4);
        float v[8];
        #pragma unroll
        for (int j = 0; j < 8; ++j) {
            const int k = kq0 + kl + j;
            float vv = 0.f;
            if (col < 4)       vv = rmsw[k] * phi_pre[k * 4 + col];
            else if (col < 8)  vv = rmsw[k] * phi_post[k * 4 + (col - 4)];
            else if (col < 24) vv = rmsw[k] * phi_res[k * 16 + (col - 8)];
            v[j] = vv;
        }
        uint4 pk;
        pk.x = cvt_pk_bf16(v[0], v[1]);
        pk.y = cvt_pk_bf16(v[2], v[3]);
        pk.z = cvt_pk_bf16(v[4], v[5]);
        pk.w = cvt_pk_bf16(v[6], v[7]);
        bfrag[(s * 2 + n) * 64 + ln] = pk;
    }
    __syncthreads();

    const int row = g * 128 + wave * 16 + (lane & 15);
    const float* xr = x + (size_t)row * KDIM + kq0 + 8 * (lane >> 4);

    f32x4 acc0 = {0.f, 0.f, 0.f, 0.f};
    f32x4 acc1 = {0.f, 0.f, 0.f, 0.f};
    float ssq = 0.f;

    #pragma unroll 4
    for (int s = 0; s < NS; ++s) {
        const float4 a0 = *(const float4*)(xr + 32 * s);
        const float4 a1 = *(const float4*)(xr + 32 * s + 4);
        ssq = fmaf(a0.x, a0.x, ssq); ssq = fmaf(a0.y, a0.y, ssq);
        ssq = fmaf(a0.z, a0.z, ssq); ssq = fmaf(a0.w, a0.w, ssq);
        ssq = fmaf(a1.x, a1.x, ssq); ssq = fmaf(a1.y, a1.y, ssq);
        ssq = fmaf(a1.z, a1.z, ssq); ssq = fmaf(a1.w, a1.w, ssq);
        BF af;
        af.u4.x = cvt_pk_bf16(a0.x, a0.y);
        af.u4.y = cvt_pk_bf16(a0.z, a0.w);
        af.u4.z = cvt_pk_bf16(a1.x, a1.y);
        af.u4.w = cvt_pk_bf16(a1.z, a1.w);
        BF b0, b1;
        b0.u4 = bfrag[(s * 2 + 0) * 64 + lane];
        b1.u4 = bfrag[(s * 2 + 1) * 64 + lane];
        acc0 = __builtin_amdgcn_mfma_f32_16x16x32_bf16(af.h, b0.h, acc0, 0, 0, 0);
        acc1 = __builtin_amdgcn_mfma_f32_16x16x32_bf16(af.h, b1.h, acc1, 0, 0, 0);
    }

    ssq += __shfl_xor(ssq, 16);
    ssq += __shfl_xor(ssq, 32);

    float* wsq = ws + (size_t)q * (NJ * ROWS_TOTAL);
    const int rbase = g * 128 + wave * 16 + 4 * (lane >> 4);
    const int c0 = lane & 15;
    #pragma unroll
    for (int r = 0; r < 4; ++r)
        wsq[c0 * ROWS_TOTAL + rbase + r] = acc0[r];
    if (c0 < 8) {
        #pragma unroll
        for (int r = 0; r < 4; ++r)
            wsq[(16 + c0) * ROWS_TOTAL + rbase + r] = acc1[r];
    }
    if (lane < 16)
        wsq[24 * ROWS_TOTAL + g * 128 + wave * 16 + lane] = ssq;
}

template<int KSPLIT>
__global__ __launch_bounds__(512) void mhc_epi2(
    const float* __restrict__ ws,
    const float* __restrict__ b_pre,
    const float* __restrict__ b_post,
    const float* __restrict__ b_res,
    const float* __restrict__ a_pre,
    const float* __restrict__ a_post,
    const float* __restrict__ a_res,
    float* __restrict__ out)
{
    __shared__ float sm[NJ * 33];
    const int t  = threadIdx.x;
    const int r0 = blockIdx.x * 32;

    {
        const int row = t & 31;
        const int j0  = t >> 5;
        float s0 = 0.f;
        #pragma unroll
        for (int q = 0; q < KSPLIT; ++q)
            s0 += ws[(size_t)q * (NJ * ROWS_TOTAL) + (size_t)j0 * ROWS_TOTAL + r0 + row];
        sm[j0 * 33 + row] = s0;
        const int j1 = 16 + j0;
        if (j1 < NJ) {
            float s1 = 0.f;
            #pragma unroll
            for (int q = 0; q < KSPLIT; ++q)
                s1 += ws[(size_t)q * (NJ * ROWS_TOTAL) + (size_t)j1 * ROWS_TOTAL + r0 + row];
            sm[j1 * 33 + row] = s1;
        }
    }
    __syncthreads();

    const int wave = t >> 6;
    const int lane = t & 63;
    const int row  = wave * 4 + (lane >> 4);
    const int cell = lane & 15;
    const int gr   = r0 + row;

    const float scale = rsqrtf(sm[24 * 33 + row] * (1.0f / KDIM) + 1e-6f);

    if (cell < 4) {
        out[gr * 4 + cell] = sigmoidf_(fmaf(a_pre[0] * scale, sm[cell * 33 + row], b_pre[cell]));
    } else if (cell < 8) {
        out[32768 + gr * 4 + (cell - 4)] =
            2.f * sigmoidf_(fmaf(a_post[0] * scale, sm[cell * 33 + row], b_post[cell - 4]));
    }

    float m = __expf(fmaf(a_res[0] * scale, sm[(8 + cell) * 33 + row], b_res[cell]));
    for (int it = 0; it < 20; ++it) {
        float s = m + __shfl_xor(m, 1);
        s += __shfl_xor(s, 2);
        m /= s;
        float c = m + __shfl_xor(m, 4);
        c += __shfl_xor(c, 8);
        m /= c;
    }
    out[65536 + gr * 16 + cell] = m;
}

extern "C" void kernel_launch(void* const* d_in, const int* in_sizes, int n_in,
                              void* d_out, int out_size, void* d_ws, size_t ws_size,
                              hipStream_t stream) {
    const float* x      = (const float*)d_in[0];
    const float* rmsw   = (const float*)d_in[1];
    const float* ppre   = (const float*)d_in[2];
    const float* ppost  = (const float*)d_in[3];
    const float* pres   = (const float*)d_in[4];
    const float* b_pre  = (const float*)d_in[5];
    const float* b_post = (const float*)d_in[6];
    const float* b_res  = (const float*)d_in[7];
    const float* a_pre  = (const float*)d_in[8];
    const float* a_post = (const float*)d_in[9];
    const float* a_res  = (const float*)d_in[10];
    float* out = (float*)d_out;

    if (ws_size >= (size_t)16384 * 16) {   // 256 KB for packed B
        uint4* packed = (uint4*)d_ws;
        hipLaunchKernelGGL(mhc_pack, dim3(32), dim3(512), 0, stream,
                           rmsw, ppre, ppost, pres, packed);
        hipLaunchKernelGGL(mhc_full, dim3(256), dim3(1024), 0, stream,
                           x, packed, b_pre, b_post, b_res,
                           a_pre, a_post, a_res, out);
    } else {
        float* ws = (float*)d_ws;          // needs 3.3 MB
        hipLaunchKernelGGL((mhc_main_legacy<4>), dim3(64 * 4), dim3(512), 0, stream,
                           x, rmsw, ppre, ppost, pres, ws);
        hipLaunchKernelGGL((mhc_epi2<4>), dim3(256), dim3(512), 0, stream,
                           ws, b_pre, b_post, b_res, a_pre, a_post, a_res, out);
    }
}